// Round 12
// baseline (150.928 us; speedup 1.0000x reference)
//
#include <hip/hip_runtime.h>
#include <hip/hip_bf16.h>

#define SEQ   101
#define BATCH 16384
#define INP   9
#define HID   32
#define NOUT  3
#define HSlin 3232          // HID*SEQ
#define SB    (SEQ * BATCH) // flattened (s,b) cols

typedef __attribute__((ext_vector_type(8))) _Float16 half8;   // 8 fp16 (4 VGPRs)
typedef __attribute__((ext_vector_type(8))) short short8;
typedef __attribute__((ext_vector_type(4))) float f32x4;      // MFMA C/D
typedef __attribute__((ext_vector_type(2))) float f32x2;      // v_pk_* pairs
typedef __attribute__((ext_vector_type(4))) unsigned u32x4;

#define LOG2E   1.4426950408889634f
#define N2LOG2E (-2.8853900817779268f)

// pack two f32 -> half2 in one v_cvt_pkrtz_f16_f32
__device__ __forceinline__ unsigned pkh(float a, float b) {
    return __builtin_bit_cast(unsigned, __builtin_amdgcn_cvt_pkrtz(a, b));
}

// Swapped-operand scheme: gates^T = W * [x|h]^T, fp16 single-pass (R11).
// Weights pre-scaled by log2e (i,f,o) / 2*log2e (g) so activations use raw exp2.
// k-permutation for h: pi(8g+j) = 4g + (j&3) + 16*(j>>2) — with 16 real cols
// the lane's OWN 8 activations are exactly its B-fragment (zero exchange).
// x map: k=0..8 -> W_ih column k; k>=9 -> 0.
__global__ void prep_kernel(const float* __restrict__ W_ih, const float* __restrict__ W_hh,
                            const float* __restrict__ b_ih, const float* __restrict__ b_hh,
                            unsigned short* __restrict__ whh16, unsigned short* __restrict__ wih16,
                            float* __restrict__ biasc) {
    int tid = threadIdx.x;            // 0..511 : t = tid>>6, l = tid&63
    int l   = tid & 63;
    int t   = tid >> 6;
    int row = l & 15;                 // gate-in-tile
    int g   = l >> 4;
    int gate = 16 * t + row;
    float sc = ((gate >> 5) == 2) ? (2.f * LOG2E) : LOG2E;    // g-gate: tanh needs e^{-2g}
    for (int j = 0; j < 8; ++j) {
        int u = 4 * g + (j & 3) + 16 * (j >> 2);     // pi(8g+j)
        _Float16 wh = (_Float16)(W_hh[gate * HID + u] * sc);
        whh16[tid * 8 + j] = __builtin_bit_cast(unsigned short, wh);
        int k = 8 * g + j;
        _Float16 wi = (_Float16)((k < INP) ? (W_ih[gate * INP + k] * sc) : 0.f);
        wih16[tid * 8 + j] = __builtin_bit_cast(unsigned short, wi);
    }
    if (tid < 4 * HID) {
        float bs = ((tid >> 5) == 2) ? (2.f * LOG2E) : LOG2E;
        biasc[tid] = (b_ih[tid] + b_hh[tid]) * bs;
    }
}

// Emit staged W_lin partials (base psb = s*BATCH + b0). 16 real cols:
// reduce over the 4 g-groups (xor16/xor32), lanes 0..15 hold col sums.
template<bool PLANES>
__device__ __forceinline__ void emit_prev(float p0, float p1, float p2,
                                          unsigned psb, float* __restrict__ dataout,
                                          int lane, int c) {
    p0 += __shfl_xor(p0, 16); p1 += __shfl_xor(p1, 16); p2 += __shfl_xor(p2, 16);
    p0 += __shfl_xor(p0, 32); p1 += __shfl_xor(p1, 32); p2 += __shfl_xor(p2, 32);
    if (PLANES) {
        if (lane < 16) {
            unsigned blk = psb + (unsigned)lane;
            dataout[0 * SB + blk] = p0;
            dataout[1 * SB + blk] = p1;
            dataout[2 * SB + blk] = p2;
        }
    } else {
        // fallback: <=2 output rows across the 16 cols; butterfly + lane-0 atomics
        unsigned blk  = psb + (unsigned)c;
        unsigned r    = blk / 101u;
        unsigned rmin = psb / 101u;
        bool low = (r == rmin);
        float a0 = low ? p0 : 0.f, a1 = low ? p1 : 0.f, a2 = low ? p2 : 0.f;
        float d0 = low ? 0.f : p0, d1 = low ? 0.f : p1, d2 = low ? 0.f : p2;
#pragma unroll
        for (int m = 1; m < 16; m <<= 1) {
            a0 += __shfl_xor(a0, m); a1 += __shfl_xor(a1, m); a2 += __shfl_xor(a2, m);
            d0 += __shfl_xor(d0, m); d1 += __shfl_xor(d1, m); d2 += __shfl_xor(d2, m);
        }
        int anyhi = __any(!low && lane < 16);
        if (lane == 0) {
            atomicAdd(&dataout[rmin * 3 + 0], a0);
            atomicAdd(&dataout[rmin * 3 + 1], a1);
            atomicAdd(&dataout[rmin * 3 + 2], a2);
            if (anyhi) {
                atomicAdd(&dataout[(rmin + 1u) * 3 + 0], d0);
                atomicAdd(&dataout[(rmin + 1u) * 3 + 1], d1);
                atomicAdd(&dataout[(rmin + 1u) * 3 + 2], d2);
            }
        }
    }
}

// One wave per 16 REAL batch rows; recurrence fully register-resident and
// fully static: lane (c,g) computes activations of its own 8 units
// {16*ht + 4g + q}, which ARE its next-step B-fragment (no selects, no
// exchange, no LDS). fp16 single-pass: 16 MFMA/step for 16 rows.
template<bool PLANES>
__global__ __launch_bounds__(64, 1) void lstm_kernel(
    const float* __restrict__ x,                 // [SEQ][BATCH][INP]
    const unsigned short* __restrict__ whh_g,    // [8][64][8] fp16 A-frags
    const unsigned short* __restrict__ wih_g,    // [8][64][8] fp16 A-frags
    const float* __restrict__ biasc,             // [4H] (pre-scaled)
    const float* __restrict__ W_lin,             // [NOUT][HSlin]
    float* __restrict__ dataout)                 // planes [3][SB] (or accp fallback)
{
    const int lane = threadIdx.x;
    const int c    = lane & 15;        // real batch col
    const int g    = lane >> 4;
    const int b0   = blockIdx.x * 16;
    const int b    = b0 + c;

    // Static A-fragments + per-lane bias quads (live across all steps)
    half8 whh[8], xw[8];
    f32x4 biasv[8];
#pragma unroll
    for (int t = 0; t < 8; ++t) {
        whh[t] = __builtin_bit_cast(half8, *reinterpret_cast<const short8*>(whh_g + (t * 64 + lane) * 8));
        xw[t]  = __builtin_bit_cast(half8, *reinterpret_cast<const short8*>(wih_g + (t * 64 + lane) * 8));
        biasv[t] = *reinterpret_cast<const f32x4*>(biasc + 16 * t + 4 * g);
    }

    const bool g0 = (g == 0), g1 = (g == 1);

    f32x2 cs[4] = {{0.f,0.f},{0.f,0.f},{0.f,0.f},{0.f,0.f}};  // c: pair p = (ht=p>>1, q=2(p&1)+{0,1})
    f32x2 hp[4] = {{0.f,0.f},{0.f,0.f},{0.f,0.f},{0.f,0.f}};  // h of my 8 units
    u32x4 bhv = {0u, 0u, 0u, 0u};                // packed fp16 h B-frag (persistent)
    float xv[9];
    {
        const float* xp = x + (size_t)b * INP;           // s = 0
#pragma unroll
        for (int i = 0; i < 9; ++i) xv[i] = xp[i];
    }

    float pp0 = 0.f, pp1 = 0.f, pp2 = 0.f;               // staged W_lin partials
    unsigned psb = 0;

#pragma unroll 1
    for (int s = 0; s < SEQ; ++s) {
        // (0) this step's W_lin weights (8 units x 3 planes, consumed late)
        unsigned blk  = (unsigned)s * BATCH + (unsigned)b;
        unsigned r    = blk / 101u;
        unsigned slot = blk - r * 101u;
        const float* wl = W_lin + slot * HID + 4 * g;
        float4 w0a = *(const float4*)(wl);
        float4 w0b = *(const float4*)(wl + 16);
        float4 w1a = *(const float4*)(wl + HSlin);
        float4 w1b = *(const float4*)(wl + HSlin + 16);
        float4 w2a = *(const float4*)(wl + 2 * HSlin);
        float4 w2b = *(const float4*)(wl + 2 * HSlin + 16);

        // (1) fp16 x B-fragment: g=0 supplies x0..x7 (k=0..7), g=1 supplies x8
        short8 xa;
        {
            unsigned x01 = pkh(xv[0], xv[1]), x23 = pkh(xv[2], xv[3]);
            unsigned x45 = pkh(xv[4], xv[5]), x67 = pkh(xv[6], xv[7]);
            unsigned x8z = pkh(xv[8], 0.f);
            u32x4 xt;
            xt[0] = g0 ? x01 : (g1 ? x8z : 0u);
            xt[1] = g0 ? x23 : 0u;
            xt[2] = g0 ? x45 : 0u;
            xt[3] = g0 ? x67 : 0u;
            xa = __builtin_bit_cast(short8, xt);
        }
        // (2) h B-fragment: own units, already packed (persistent)
        half8 bh = __builtin_bit_cast(half8, bhv);

        // (3) gates^T: 8 tiles x 2 MFMA (fp16, fp32-accum)
        f32x4 acc[8];
#pragma unroll
        for (int t = 0; t < 8; ++t) {
            acc[t] = __builtin_amdgcn_mfma_f32_16x16x32_f16(xw[t], __builtin_bit_cast(half8, xa), biasv[t], 0, 0, 0);
            acc[t] = __builtin_amdgcn_mfma_f32_16x16x32_f16(whh[t], bh, acc[t], 0, 0, 0);
        }
        // (4) previous step's reduce + stores — hides under MFMA latency
        if (s > 0) emit_prev<PLANES>(pp0, pp1, pp2, psb, dataout, lane, c);

        // (5) prefetch next step's x
        float xn[9];
        if (s < SEQ - 1) {
            const float* xpn = x + ((size_t)(s + 1) * BATCH + b) * INP;
#pragma unroll
            for (int i = 0; i < 9; ++i) xn[i] = xpn[i];
        }

        // (6) activations: 4 STATIC pairs p=(ht,qpair) — no selects, no exchange.
        //     c' = [c*(1+ei)(1+eg) + (1-eg)(1+ef)] / [(1+ef)(1+ei)(1+eg)]
        //     h  = (1-ec) / ((1+eo)(1+ec)),  ec = exp2(c' * -2log2e)
#pragma unroll
        for (int p = 0; p < 4; ++p) {
            const int ht = p >> 1, q0 = 2 * (p & 1);
            f32x2 aI = {acc[0 + ht][q0], acc[0 + ht][q0 + 1]};
            f32x2 aF = {acc[2 + ht][q0], acc[2 + ht][q0 + 1]};
            f32x2 aG = {acc[4 + ht][q0], acc[4 + ht][q0 + 1]};
            f32x2 aO = {acc[6 + ht][q0], acc[6 + ht][q0 + 1]};
            f32x2 ef = {__builtin_amdgcn_exp2f(-aF.x), __builtin_amdgcn_exp2f(-aF.y)};
            f32x2 ei = {__builtin_amdgcn_exp2f(-aI.x), __builtin_amdgcn_exp2f(-aI.y)};
            f32x2 eg = {__builtin_amdgcn_exp2f(-aG.x), __builtin_amdgcn_exp2f(-aG.y)};
            f32x2 pf = ef + 1.f;
            f32x2 A  = (ei + 1.f) * (eg + 1.f);
            f32x2 num = cs[p] * A + (1.f - eg) * pf;
            f32x2 den = pf * A;
            f32x2 rd = {__builtin_amdgcn_rcpf(den.x), __builtin_amdgcn_rcpf(den.y)};
            f32x2 cn = num * rd;
            cs[p] = cn;
            f32x2 eo = {__builtin_amdgcn_exp2f(-aO.x), __builtin_amdgcn_exp2f(-aO.y)};
            f32x2 ec = {__builtin_amdgcn_exp2f(cn.x * N2LOG2E), __builtin_amdgcn_exp2f(cn.y * N2LOG2E)};
            f32x2 dd = (eo + 1.f) * (ec + 1.f);
            f32x2 rh = {__builtin_amdgcn_rcpf(dd.x), __builtin_amdgcn_rcpf(dd.y)};
            hp[p] = (1.f - ec) * rh;
        }
        // (6b) pack next-step B-fragment directly from own pairs (4 pkh, static)
        bhv[0] = pkh(hp[0].x, hp[0].y);
        bhv[1] = pkh(hp[1].x, hp[1].y);
        bhv[2] = pkh(hp[2].x, hp[2].y);
        bhv[3] = pkh(hp[3].x, hp[3].y);
        if (s < SEQ - 1) {
#pragma unroll
            for (int i = 0; i < 9; ++i) xv[i] = xn[i];
        }

        // (7) this step's W_lin partials — all 8 of my units
        pp0 = w0a.x*hp[0].x + w0a.y*hp[0].y + w0a.z*hp[1].x + w0a.w*hp[1].y
            + w0b.x*hp[2].x + w0b.y*hp[2].y + w0b.z*hp[3].x + w0b.w*hp[3].y;
        pp1 = w1a.x*hp[0].x + w1a.y*hp[0].y + w1a.z*hp[1].x + w1a.w*hp[1].y
            + w1b.x*hp[2].x + w1b.y*hp[2].y + w1b.z*hp[3].x + w1b.w*hp[3].y;
        pp2 = w2a.x*hp[0].x + w2a.y*hp[0].y + w2a.z*hp[1].x + w2a.w*hp[1].y
            + w2b.x*hp[2].x + w2b.y*hp[2].y + w2b.z*hp[3].x + w2b.w*hp[3].y;
        psb = (unsigned)s * BATCH + (unsigned)b0;
    }
    // epilogue: emit for s = SEQ-1
    emit_prev<PLANES>(pp0, pp1, pp2, psb, dataout, lane, c);
}

// Plane path: one wave per output row sums its 101 contiguous cols.
__global__ void finalize_planes(const float* __restrict__ planes, const float* __restrict__ b_lin,
                                float* __restrict__ out) {
    int wid = (blockIdx.x * blockDim.x + threadIdx.x) >> 6;   // row 0..16383
    int l   = threadIdx.x & 63;
    float v[3];
#pragma unroll
    for (int o = 0; o < 3; ++o) {
        const float* p = planes + (size_t)o * SB + (size_t)wid * 101;
        float t = p[l] + ((l < 37) ? p[l + 64] : 0.f);
#pragma unroll
        for (int m = 1; m < 64; m <<= 1) t += __shfl_xor(t, m);
        v[o] = t;
    }
    if (l == 0) {
        out[wid * 3 + 0] = v[0] + b_lin[0];
        out[wid * 3 + 1] = v[1] + b_lin[1];
        out[wid * 3 + 2] = v[2] + b_lin[2];
    }
}

__global__ void finalize_acc(const float* __restrict__ acc, const float* __restrict__ b_lin,
                             float* __restrict__ out) {
    int i = blockIdx.x * blockDim.x + threadIdx.x;
    if (i < BATCH * NOUT) {
        int r = i / 3;
        int o = i - r * 3;
        out[i] = acc[i] + b_lin[o];
    }
}

extern "C" void kernel_launch(void* const* d_in, const int* in_sizes, int n_in,
                              void* d_out, int out_size, void* d_ws, size_t ws_size,
                              hipStream_t stream) {
    const float* x     = (const float*)d_in[0];
    const float* W_ih  = (const float*)d_in[1];
    const float* W_hh  = (const float*)d_in[2];
    const float* b_ih  = (const float*)d_in[3];
    const float* b_hh  = (const float*)d_in[4];
    const float* W_lin = (const float*)d_in[5];
    const float* b_lin = (const float*)d_in[6];
    float* out = (float*)d_out;

    // ws: whh16[4096]u16 | wih16[4096]u16 | biasc[128]f32 | (pad) | data...
    unsigned short* whh16 = (unsigned short*)d_ws;
    unsigned short* wih16 = whh16 + 4096;
    float* biasc = (float*)(wih16 + 4096);
    float* data  = (float*)((char*)d_ws + 25600);

    size_t need_planes = 25600 + (size_t)3 * SB * sizeof(float);
    bool planes = ws_size >= need_planes;

    hipLaunchKernelGGL(prep_kernel, dim3(1), dim3(512), 0, stream,
                       W_ih, W_hh, b_ih, b_hh, whh16, wih16, biasc);
    if (planes) {
        hipLaunchKernelGGL((lstm_kernel<true>), dim3(BATCH / 16), dim3(64), 0, stream,
                           x, whh16, wih16, biasc, W_lin, data);
        hipLaunchKernelGGL(finalize_planes, dim3(BATCH / 4), dim3(256), 0, stream,
                           data, b_lin, out);
    } else {
        hipMemsetAsync(data, 0, 49160 * sizeof(float), stream);
        hipLaunchKernelGGL((lstm_kernel<false>), dim3(BATCH / 16), dim3(64), 0, stream,
                           x, whh16, wih16, biasc, W_lin, data);
        hipLaunchKernelGGL(finalize_acc, dim3((BATCH * NOUT + 255) / 256), dim3(256), 0, stream,
                           data, b_lin, out);
    }
}

// Round 13
// 117.133 us; speedup vs baseline: 1.2885x; 1.2885x over previous
//
#include <hip/hip_runtime.h>
#include <hip/hip_bf16.h>

#define SEQ   101
#define BATCH 16384
#define INP   9
#define HID   32
#define NOUT  3
#define HSlin 3232          // HID*SEQ
#define SB    (SEQ * BATCH) // flattened (s,b) cols

typedef __attribute__((ext_vector_type(8))) _Float16 half8;   // 8 fp16 (4 VGPRs)
typedef __attribute__((ext_vector_type(8))) short short8;
typedef __attribute__((ext_vector_type(4))) float f32x4;      // MFMA C/D
typedef __attribute__((ext_vector_type(2))) float f32x2;      // v_pk_* pairs
typedef __attribute__((ext_vector_type(4))) unsigned u32x4;

#define LOG2E   1.4426950408889634f
#define N2LOG2E (-2.8853900817779268f)

// pack two f32 -> half2 in one v_cvt_pkrtz_f16_f32
__device__ __forceinline__ unsigned pkh(float a, float b) {
    return __builtin_bit_cast(unsigned, __builtin_amdgcn_cvt_pkrtz(a, b));
}
// DPP row_ror:8 — within each 16-lane row, lane i <-> lane i^8
__device__ __forceinline__ unsigned dpp8u(unsigned v) {
    return (unsigned)__builtin_amdgcn_mov_dpp((int)v, 0x128, 0xF, 0xF, true);
}
__device__ __forceinline__ float dpp8f(float v) {
    return __int_as_float(__builtin_amdgcn_mov_dpp(__float_as_int(v), 0x128, 0xF, 0xF, true));
}

// Swapped-operand scheme: gates^T = W * [x|h]^T, fp16 single-pass (R11).
// Weights pre-scaled by log2e (i,f,o) / 2*log2e (g) so activations use raw exp2.
// k-permutation for h: pi(8g+j) = 4g + (j&3) + 16*(j>>2).
// x map: k=0..8 -> W_ih column k; k>=9 -> 0.
__global__ void prep_kernel(const float* __restrict__ W_ih, const float* __restrict__ W_hh,
                            const float* __restrict__ b_ih, const float* __restrict__ b_hh,
                            unsigned short* __restrict__ whh16, unsigned short* __restrict__ wih16,
                            float* __restrict__ biasc) {
    int tid = threadIdx.x;            // 0..511 : t = tid>>6, l = tid&63
    int l   = tid & 63;
    int t   = tid >> 6;
    int row = l & 15;                 // gate-in-tile
    int g   = l >> 4;
    int gate = 16 * t + row;
    float sc = ((gate >> 5) == 2) ? (2.f * LOG2E) : LOG2E;    // g-gate: tanh needs e^{-2g}
    for (int j = 0; j < 8; ++j) {
        int u = 4 * g + (j & 3) + 16 * (j >> 2);     // pi(8g+j)
        _Float16 wh = (_Float16)(W_hh[gate * HID + u] * sc);
        whh16[tid * 8 + j] = __builtin_bit_cast(unsigned short, wh);
        int k = 8 * g + j;
        _Float16 wi = (_Float16)((k < INP) ? (W_ih[gate * INP + k] * sc) : 0.f);
        wih16[tid * 8 + j] = __builtin_bit_cast(unsigned short, wi);
    }
    if (tid < 4 * HID) {
        float bs = ((tid >> 5) == 2) ? (2.f * LOG2E) : LOG2E;
        biasc[tid] = (b_ih[tid] + b_hh[tid]) * bs;
    }
}

// Emit staged W_lin partials (base psb = s*BATCH + b0). xor8 merge via DPP;
// xor16/32 via shuffle (off critical path).
template<bool PLANES>
__device__ __forceinline__ void emit_prev(float p0, float p1, float p2,
                                          unsigned psb, float* __restrict__ dataout,
                                          int lane, int cr) {
    p0 += dpp8f(p0);          p1 += dpp8f(p1);          p2 += dpp8f(p2);
    p0 += __shfl_xor(p0, 16); p1 += __shfl_xor(p1, 16); p2 += __shfl_xor(p2, 16);
    p0 += __shfl_xor(p0, 32); p1 += __shfl_xor(p1, 32); p2 += __shfl_xor(p2, 32);
    if (PLANES) {
        if (lane < 8) {
            unsigned blk = psb + (unsigned)lane;
            dataout[0 * SB + blk] = p0;
            dataout[1 * SB + blk] = p1;
            dataout[2 * SB + blk] = p2;
        }
    } else {
        // fallback: <=2 output rows across the 8 cols; butterfly + lane-0 atomics
        unsigned blk  = psb + (unsigned)cr;
        unsigned r    = blk / 101u;
        unsigned rmin = psb / 101u;
        bool low = (r == rmin);
        float a0 = low ? p0 : 0.f, a1 = low ? p1 : 0.f, a2 = low ? p2 : 0.f;
        float d0 = low ? 0.f : p0, d1 = low ? 0.f : p1, d2 = low ? 0.f : p2;
#pragma unroll
        for (int m = 1; m < 8; m <<= 1) {
            a0 += __shfl_xor(a0, m); a1 += __shfl_xor(a1, m); a2 += __shfl_xor(a2, m);
            d0 += __shfl_xor(d0, m); d1 += __shfl_xor(d1, m); d2 += __shfl_xor(d2, m);
        }
        int anyhi = __any(!low && lane < 8);
        if (lane == 0) {
            atomicAdd(&dataout[rmin * 3 + 0], a0);
            atomicAdd(&dataout[rmin * 3 + 1], a1);
            atomicAdd(&dataout[rmin * 3 + 2], a2);
            if (anyhi) {
                atomicAdd(&dataout[(rmin + 1u) * 3 + 0], d0);
                atomicAdd(&dataout[(rmin + 1u) * 3 + 1], d1);
                atomicAdd(&dataout[(rmin + 1u) * 3 + 2], d2);
            }
        }
    }
}

// One INDEPENDENT wave per 8 batch rows (cols 8-15 duplicate 0-7), no barriers,
// 2 waves/SIMD. fp16 single-pass gates. NEW vs R11: x-projection MFMAs for
// step s+1 are hoisted into step s (xacc pipeline) so each step's matrix
// chain is 1-deep; W_lin slot via running +22 mod 101 (no per-step division).
template<bool PLANES>
__global__ __launch_bounds__(64, 2) void lstm_kernel(
    const float* __restrict__ x,                 // [SEQ][BATCH][INP]
    const unsigned short* __restrict__ whh_g,    // [8][64][8] fp16 A-frags
    const unsigned short* __restrict__ wih_g,    // [8][64][8] fp16 A-frags
    const float* __restrict__ biasc,             // [4H] (pre-scaled)
    const float* __restrict__ W_lin,             // [NOUT][HSlin]
    float* __restrict__ dataout)                 // planes [3][SB] (or accp fallback)
{
    const int lane = threadIdx.x;
    const int c    = lane & 15;        // MFMA batch col
    const int cr   = c & 7;            // real batch col (8-15 duplicate 0-7)
    const bool hi8 = (lane & 8) != 0;  // this lane owns half1 (units 16+4g+q)
    const int g    = lane >> 4;
    const int b0   = blockIdx.x * 8;
    const int b    = b0 + cr;

    // Static A-fragments + per-lane bias quads (live across all steps)
    half8 whh[8], xw[8];
    f32x4 biasv[8];
#pragma unroll
    for (int t = 0; t < 8; ++t) {
        whh[t] = __builtin_bit_cast(half8, *reinterpret_cast<const short8*>(whh_g + (t * 64 + lane) * 8));
        xw[t]  = __builtin_bit_cast(half8, *reinterpret_cast<const short8*>(wih_g + (t * 64 + lane) * 8));
        biasv[t] = *reinterpret_cast<const f32x4*>(biasc + 16 * t + 4 * g);
    }

    const bool g0 = (g == 0), g1 = (g == 1);

    f32x2 cs[2] = {{0.f, 0.f}, {0.f, 0.f}};      // c-state: my half's 4 units
    f32x2 ho[2] = {{0.f, 0.f}, {0.f, 0.f}};      // my half's h (for W_lin dot)
    u32x4 bhv = {0u, 0u, 0u, 0u};                // packed fp16 h B-frag (persistent)

    // ---- prologue: xacc(0) = x-projection of step 0; xv holds x(1) ----
    f32x4 xacc[8];
    float xv[9];
    {
        const float* xp = x + (size_t)b * INP;
#pragma unroll
        for (int i = 0; i < 9; ++i) xv[i] = xp[i];
        unsigned x01 = pkh(xv[0], xv[1]), x23 = pkh(xv[2], xv[3]);
        unsigned x45 = pkh(xv[4], xv[5]), x67 = pkh(xv[6], xv[7]);
        unsigned x8z = pkh(xv[8], 0.f);
        u32x4 xt;
        xt[0] = g0 ? x01 : (g1 ? x8z : 0u);
        xt[1] = g0 ? x23 : 0u;
        xt[2] = g0 ? x45 : 0u;
        xt[3] = g0 ? x67 : 0u;
        half8 xa = __builtin_bit_cast(half8, xt);
#pragma unroll
        for (int t = 0; t < 8; ++t)
            xacc[t] = __builtin_amdgcn_mfma_f32_16x16x32_f16(xw[t], xa, biasv[t], 0, 0, 0);
        const float* xp1 = x + ((size_t)BATCH + b) * INP;
#pragma unroll
        for (int i = 0; i < 9; ++i) xv[i] = xp1[i];
    }

    // running W_lin column: slot = (s*BATCH + b) mod 101; BATCH ≡ 22 (mod 101)
    unsigned rr   = (unsigned)b / 101u;
    unsigned slot = (unsigned)b - rr * 101u;

    float pp0 = 0.f, pp1 = 0.f, pp2 = 0.f;       // staged W_lin partials
    unsigned psb = 0;

#pragma unroll 1
    for (int s = 0; s < SEQ; ++s) {
        // (0) this step's W_lin weights — my half's 4 columns per plane
        const float* wl = W_lin + slot * HID + 4 * g + (hi8 ? 16 : 0);
        float4 w0 = *(const float4*)(wl);
        float4 w1 = *(const float4*)(wl + HSlin);
        float4 w2 = *(const float4*)(wl + 2 * HSlin);

        // (1) gates^T: 1-deep h-MFMA chain on precomputed xacc
        half8 bh = __builtin_bit_cast(half8, bhv);
        f32x4 acc[8];
#pragma unroll
        for (int t = 0; t < 8; ++t)
            acc[t] = __builtin_amdgcn_mfma_f32_16x16x32_f16(whh[t], bh, xacc[t], 0, 0, 0);

        // (2) previous step's reduce + stores — hides under MFMA latency
        if (s > 0) emit_prev<PLANES>(pp0, pp1, pp2, psb, dataout, lane, cr);

        // (3) next step's x-projection (independent of h) — fills MFMA shadow
        if (s + 1 < SEQ) {
            unsigned x01 = pkh(xv[0], xv[1]), x23 = pkh(xv[2], xv[3]);
            unsigned x45 = pkh(xv[4], xv[5]), x67 = pkh(xv[6], xv[7]);
            unsigned x8z = pkh(xv[8], 0.f);
            u32x4 xt;
            xt[0] = g0 ? x01 : (g1 ? x8z : 0u);
            xt[1] = g0 ? x23 : 0u;
            xt[2] = g0 ? x45 : 0u;
            xt[3] = g0 ? x67 : 0u;
            half8 xa = __builtin_bit_cast(half8, xt);
#pragma unroll
            for (int t = 0; t < 8; ++t)
                xacc[t] = __builtin_amdgcn_mfma_f32_16x16x32_f16(xw[t], xa, biasv[t], 0, 0, 0);
        }
        // (4) prefetch x(s+2)
        float xn[9];
        if (s + 2 < SEQ) {
            const float* xpn = x + ((size_t)(s + 2) * BATCH + b) * INP;
#pragma unroll
            for (int i = 0; i < 9; ++i) xn[i] = xpn[i];
        }

        // (5) activations for MY half (4 units as 2 float2 pairs, v_pk math).
        //     c' = [c*(1+ei)(1+eg) + (1-eg)(1+ef)] / [(1+ef)(1+ei)(1+eg)]
        //     h  = (1-ec) / ((1+eo)(1+ec)),  ec = exp2(c' * -2log2e)
        f32x4 aI = hi8 ? acc[1] : acc[0];
        f32x4 aF = hi8 ? acc[3] : acc[2];
        f32x4 aG = hi8 ? acc[5] : acc[4];
        f32x4 aO = hi8 ? acc[7] : acc[6];
#pragma unroll
        for (int p = 0; p < 2; ++p) {
            f32x2 ef = {__builtin_amdgcn_exp2f(-aF[2*p]), __builtin_amdgcn_exp2f(-aF[2*p+1])};
            f32x2 ei = {__builtin_amdgcn_exp2f(-aI[2*p]), __builtin_amdgcn_exp2f(-aI[2*p+1])};
            f32x2 eg = {__builtin_amdgcn_exp2f(-aG[2*p]), __builtin_amdgcn_exp2f(-aG[2*p+1])};
            f32x2 pf = ef + 1.f;
            f32x2 A  = (ei + 1.f) * (eg + 1.f);
            f32x2 num = cs[p] * A + (1.f - eg) * pf;
            f32x2 den = pf * A;
            f32x2 rd = {__builtin_amdgcn_rcpf(den.x), __builtin_amdgcn_rcpf(den.y)};
            f32x2 cn = num * rd;
            cs[p] = cn;
            f32x2 eo = {__builtin_amdgcn_exp2f(-aO[2*p]), __builtin_amdgcn_exp2f(-aO[2*p+1])};
            f32x2 ec = {__builtin_amdgcn_exp2f(cn.x * N2LOG2E), __builtin_amdgcn_exp2f(cn.y * N2LOG2E)};
            f32x2 dd = (eo + 1.f) * (ec + 1.f);
            f32x2 rh = {__builtin_amdgcn_rcpf(dd.x), __builtin_amdgcn_rcpf(dd.y)};
            ho[p] = (1.f - ec) * rh;
        }
        // (5b) pack own half to fp16, DPP-exchange with twin, order into B-frag
        {
            unsigned oh01 = pkh(ho[0].x, ho[0].y);
            unsigned oh23 = pkh(ho[1].x, ho[1].y);
            unsigned th01 = dpp8u(oh01), th23 = dpp8u(oh23);
            bhv[0] = hi8 ? th01 : oh01;  bhv[1] = hi8 ? th23 : oh23;
            bhv[2] = hi8 ? oh01 : th01;  bhv[3] = hi8 ? oh23 : th23;
        }
        if (s + 2 < SEQ) {
#pragma unroll
            for (int i = 0; i < 9; ++i) xv[i] = xn[i];
        }

        // (6) this step's W_lin partial — my half's 4 units only
        pp0 = w0.x * ho[0].x + w0.y * ho[0].y + w0.z * ho[1].x + w0.w * ho[1].y;
        pp1 = w1.x * ho[0].x + w1.y * ho[0].y + w1.z * ho[1].x + w1.w * ho[1].y;
        pp2 = w2.x * ho[0].x + w2.y * ho[0].y + w2.z * ho[1].x + w2.w * ho[1].y;
        psb = ((unsigned)s << 14) + (unsigned)b0;            // s*BATCH + b0

        // advance slot: (slot + BATCH) mod 101, BATCH ≡ 22
        slot += 22u;
        slot = (slot >= 101u) ? (slot - 101u) : slot;
    }
    // epilogue: emit for s = SEQ-1
    emit_prev<PLANES>(pp0, pp1, pp2, psb, dataout, lane, cr);
}

// Plane path: one wave per output row sums its 101 contiguous cols.
__global__ void finalize_planes(const float* __restrict__ planes, const float* __restrict__ b_lin,
                                float* __restrict__ out) {
    int wid = (blockIdx.x * blockDim.x + threadIdx.x) >> 6;   // row 0..16383
    int l   = threadIdx.x & 63;
    float v[3];
#pragma unroll
    for (int o = 0; o < 3; ++o) {
        const float* p = planes + (size_t)o * SB + (size_t)wid * 101;
        float t = p[l] + ((l < 37) ? p[l + 64] : 0.f);
#pragma unroll
        for (int m = 1; m < 64; m <<= 1) t += __shfl_xor(t, m);
        v[o] = t;
    }
    if (l == 0) {
        out[wid * 3 + 0] = v[0] + b_lin[0];
        out[wid * 3 + 1] = v[1] + b_lin[1];
        out[wid * 3 + 2] = v[2] + b_lin[2];
    }
}

__global__ void finalize_acc(const float* __restrict__ acc, const float* __restrict__ b_lin,
                             float* __restrict__ out) {
    int i = blockIdx.x * blockDim.x + threadIdx.x;
    if (i < BATCH * NOUT) {
        int r = i / 3;
        int o = i - r * 3;
        out[i] = acc[i] + b_lin[o];
    }
}

extern "C" void kernel_launch(void* const* d_in, const int* in_sizes, int n_in,
                              void* d_out, int out_size, void* d_ws, size_t ws_size,
                              hipStream_t stream) {
    const float* x     = (const float*)d_in[0];
    const float* W_ih  = (const float*)d_in[1];
    const float* W_hh  = (const float*)d_in[2];
    const float* b_ih  = (const float*)d_in[3];
    const float* b_hh  = (const float*)d_in[4];
    const float* W_lin = (const float*)d_in[5];
    const float* b_lin = (const float*)d_in[6];
    float* out = (float*)d_out;

    // ws: whh16[4096]u16 | wih16[4096]u16 | biasc[128]f32 | (pad) | data...
    unsigned short* whh16 = (unsigned short*)d_ws;
    unsigned short* wih16 = whh16 + 4096;
    float* biasc = (float*)(wih16 + 4096);
    float* data  = (float*)((char*)d_ws + 25600);

    size_t need_planes = 25600 + (size_t)3 * SB * sizeof(float);
    bool planes = ws_size >= need_planes;

    hipLaunchKernelGGL(prep_kernel, dim3(1), dim3(512), 0, stream,
                       W_ih, W_hh, b_ih, b_hh, whh16, wih16, biasc);
    if (planes) {
        hipLaunchKernelGGL((lstm_kernel<true>), dim3(BATCH / 8), dim3(64), 0, stream,
                           x, whh16, wih16, biasc, W_lin, data);
        hipLaunchKernelGGL(finalize_planes, dim3(BATCH / 4), dim3(256), 0, stream,
                           data, b_lin, out);
    } else {
        hipMemsetAsync(data, 0, 49160 * sizeof(float), stream);
        hipLaunchKernelGGL((lstm_kernel<false>), dim3(BATCH / 8), dim3(64), 0, stream,
                           x, whh16, wih16, biasc, W_lin, data);
        hipLaunchKernelGGL(finalize_acc, dim3((BATCH * NOUT + 255) / 256), dim3(256), 0, stream,
                           data, b_lin, out);
    }
}